// Round 10
// baseline (127.958 us; speedup 1.0000x reference)
//
#include <hip/hip_runtime.h>

#define BATCH 131072
#define NS    300
#define H     100
#define BLK   256
#define EPB   64                  /* elements per block: 2048 blocks -> 8 rounds/CU, phase overlap */
#define NBLK  (BATCH / EPB)
#define NQ4   (EPB * NS / 4)      /* 4800 float4 outputs per block */

#define REP25(M) M(0) M(1) M(2) M(3) M(4) M(5) M(6) M(7) M(8) M(9) M(10) M(11) \
  M(12) M(13) M(14) M(15) M(16) M(17) M(18) M(19) M(20) M(21) M(22) M(23) M(24)

__device__ __forceinline__ float qswap1(float x) {   /* quad_perm [1,0,3,2] */
    return __int_as_float(__builtin_amdgcn_mov_dpp(__float_as_int(x), 0xB1, 0xF, 0xF, true));
}
__device__ __forceinline__ float qswap2(float x) {   /* quad_perm [2,3,0,1] */
    return __int_as_float(__builtin_amdgcn_mov_dpp(__float_as_int(x), 0x4E, 0xF, 0xF, true));
}

__global__ __launch_bounds__(BLK, 2)
void lorentz_fused(const float* __restrict__ G,   const float* __restrict__ W1,
                   const float* __restrict__ b1,  const float* __restrict__ W2,
                   const float* __restrict__ b2,  const float* __restrict__ Ww0,
                   const float* __restrict__ Wwp, const float* __restrict__ Wg,
                   float* __restrict__ out)
{
    /* 51200 B LDS -> 3 blocks/CU.
       Phase A: [0,44800) W2 chunks [j][q][28] as 7 float4; [44800,51200) heads.
       Phase B: sP0/sP1/sP2 (3 x 1024 B) alias the dead W2 region. */
    __shared__ __align__(16) char smem[51200];
    float4* sW2c4  = (float4*)smem;
    float4* sHead4 = (float4*)(smem + 44800);
    float4* sP0    = (float4*)smem;             /* EPB float4 = 1024 B each (alias) */
    float4* sP1    = (float4*)(smem + 1024);
    float4* sP2    = (float4*)(smem + 2048);

    const int tid = threadIdx.x;

    /* ---- stage W2 (chunked) + heads ---- */
    {
        float* sW2cF = (float*)sW2c4;
        for (int i = tid; i < H * H; i += BLK) {
            int j = i / 100, k = i - j * 100;
            int q = k / 25, kk = k - q * 25;
            sW2cF[(j * 4 + q) * 28 + kk] = W2[i];
        }
        float* sHeadF = (float*)sHead4;
        for (int i = tid; i < H * 4; i += BLK) {
            int j = i >> 2, q = i & 3;
            sHeadF[i * 4 + 0] = Ww0[q * H + j];
            sHeadF[i * 4 + 1] = Wwp[q * H + j];
            sHeadF[i * 4 + 2] = Wg [q * H + j];
            sHeadF[i * 4 + 3] = 0.f;
        }
    }
    __syncthreads();

    const int q  = tid & 3;          /* k-chunk / oscillator owner */
    const int el = tid >> 2;         /* element 0..63; quad of lanes cooperates */
    const int e0 = blockIdx.x * EPB + el;

    /* ---- input (quad lanes read same 32B -> coalesced broadcast) ---- */
    const float4* gp = (const float4*)(G + (size_t)e0 * 8);
    const float4 gA = gp[0], gB = gp[1];

    /* ---- layer 1: lane computes h1[q*25 .. q*25+24] for ONE element.
       W1/b1 straight from global (3.6 KB, L1-resident; 4 distinct rows/wave). ---- */
#define H1DECL(i) float h1_##i;
    REP25(H1DECL)
#undef H1DECL
#define L1(i) { const float4* r = (const float4*)(W1 + (q * 25 + (i)) * 8);     \
        const float4 ra = r[0], rb = r[1];                                      \
        float s0 = fmaf(gA.x, ra.x, b1[q * 25 + (i)]);                          \
        float s1 = gA.y * ra.y;                                                 \
        s0 = fmaf(gA.z, ra.z, s0);  s1 = fmaf(gA.w, ra.w, s1);                  \
        s0 = fmaf(gB.x, rb.x, s0);  s1 = fmaf(gB.y, rb.y, s1);                  \
        s0 = fmaf(gB.z, rb.z, s0);  s1 = fmaf(gB.w, rb.w, s1);                  \
        h1_##i = fmaxf(s0 + s1, 0.f); }
    REP25(L1)
#undef L1

    /* ---- layer 2 + heads: per j, 25-fma partial dot (4 chains), DPP quad
       butterfly completes the 100-sum, heads accumulate osc q. ~80 live regs. ---- */
    float aw0 = 0.f, awp = 0.f, agg = 0.f;

#pragma unroll 1
    for (int j = 0; j < H; ++j) {
        const int cb = (j * 4 + q) * 7;
        const float4 c0 = sW2c4[cb + 0], c1 = sW2c4[cb + 1], c2 = sW2c4[cb + 2],
                     c3 = sW2c4[cb + 3], c4 = sW2c4[cb + 4], c5 = sW2c4[cb + 5],
                     c6 = sW2c4[cb + 6];
        const float4 hv  = sHead4[j * 4 + q];
        const float  b2j = b2[j];                /* wave-uniform -> s_load */

        float p0 = 0.f, p1 = 0.f, p2 = 0.f, p3 = 0.f;
        p0 = fmaf(h1_0,  c0.x, p0); p1 = fmaf(h1_1,  c0.y, p1);
        p2 = fmaf(h1_2,  c0.z, p2); p3 = fmaf(h1_3,  c0.w, p3);
        p0 = fmaf(h1_4,  c1.x, p0); p1 = fmaf(h1_5,  c1.y, p1);
        p2 = fmaf(h1_6,  c1.z, p2); p3 = fmaf(h1_7,  c1.w, p3);
        p0 = fmaf(h1_8,  c2.x, p0); p1 = fmaf(h1_9,  c2.y, p1);
        p2 = fmaf(h1_10, c2.z, p2); p3 = fmaf(h1_11, c2.w, p3);
        p0 = fmaf(h1_12, c3.x, p0); p1 = fmaf(h1_13, c3.y, p1);
        p2 = fmaf(h1_14, c3.z, p2); p3 = fmaf(h1_15, c3.w, p3);
        p0 = fmaf(h1_16, c4.x, p0); p1 = fmaf(h1_17, c4.y, p1);
        p2 = fmaf(h1_18, c4.z, p2); p3 = fmaf(h1_19, c4.w, p3);
        p0 = fmaf(h1_20, c5.x, p0); p1 = fmaf(h1_21, c5.y, p1);
        p2 = fmaf(h1_22, c5.z, p2); p3 = fmaf(h1_23, c5.w, p3);
        p0 = fmaf(h1_24, c6.x, p0);

        float pa = (p0 + p1) + (p2 + p3);
        float sa = pa + qswap1(pa); sa += qswap2(sa);
        const float h2 = fmaxf(sa + b2j, 0.f);

        aw0 = fmaf(h2, hv.x, aw0); awp = fmaf(h2, hv.y, awp); agg = fmaf(h2, hv.z, agg);
    }

    /* ---- all W2c reads done; repurpose LDS for param tables ---- */
    __syncthreads();
    {
        float* P0 = (float*)sP0; float* P1 = (float*)sP1; float* P2 = (float*)sP2;
        const float w0 = fmaxf(aw0, 0.f), wp = fmaxf(awp, 0.f), gg = fmaxf(agg, 0.f);
        const int ix = el * 4 + q;
        P0[ix] = w0 * w0;  P1[ix] = gg * gg;  P2[ix] = wp * wp * gg;
    }
    __syncthreads();

    /* ---- spectrum: block's contiguous 64*300-float region, float4 stores.
       18 full iterations + 192-thread tail (4800 = 18*256 + 192). ---- */
    float4* out4 = (float4*)out;
    const size_t base4 = (size_t)blockIdx.x * NQ4;

#define SPEC(idx4)                                                              \
    {   const int e  = (idx4) / 75;                                             \
        const int k4 = (idx4) - e * 75;                                         \
        const float4 P0 = sP0[e], P1 = sP1[e], P2 = sP2[e];                     \
        const float kb = (float)(k4 << 2);                                      \
        float4 r; float* rp = (float*)&r;                                       \
        _Pragma("unroll")                                                       \
        for (int i = 0; i < 4; ++i) {                                           \
            const float w   = 0.5f + (kb + (float)i) * 0.015f;                  \
            const float wsq = w * w;                                            \
            const float t0 = P0.x - wsq, t1 = P0.y - wsq,                       \
                        t2 = P0.z - wsq, t3 = P0.w - wsq;                       \
            const float d0 = fmaf(t0, t0, wsq * P1.x);                          \
            const float d1 = fmaf(t1, t1, wsq * P1.y);                          \
            const float d2 = fmaf(t2, t2, wsq * P1.z);                          \
            const float d3 = fmaf(t3, t3, wsq * P1.w);                          \
            const float d01 = d0 * d1, d23 = d2 * d3;                           \
            const float D   = d01 * d23;                                        \
            const float n01 = fmaf(P2.y, d0, P2.x * d1);                        \
            const float n23 = fmaf(P2.w, d2, P2.z * d3);                        \
            const float N   = fmaf(n01, d23, n23 * d01);                        \
            rp[i] = w * (N * __builtin_amdgcn_rcpf(D));                         \
        }                                                                       \
        out4[base4 + (idx4)] = r; }

    for (int it = 0; it < NQ4 / BLK; ++it) {        /* 18 iterations */
        const int idx4 = it * BLK + tid;
        SPEC(idx4)
    }
    if (tid < NQ4 - (NQ4 / BLK) * BLK) {            /* tail: 192 quads */
        const int idx4 = (NQ4 / BLK) * BLK + tid;
        SPEC(idx4)
    }
#undef SPEC
}

extern "C" void kernel_launch(void* const* d_in, const int* in_sizes, int n_in,
                              void* d_out, int out_size, void* d_ws, size_t ws_size,
                              hipStream_t stream) {
    const float* G   = (const float*)d_in[0];
    const float* W1  = (const float*)d_in[1];
    const float* b1  = (const float*)d_in[2];
    const float* W2  = (const float*)d_in[3];
    const float* b2  = (const float*)d_in[4];
    const float* Ww0 = (const float*)d_in[5];
    const float* Wwp = (const float*)d_in[6];
    const float* Wg  = (const float*)d_in[7];
    float* out = (float*)d_out;

    lorentz_fused<<<NBLK, BLK, 0, stream>>>(G, W1, b1, W2, b2, Ww0, Wwp, Wg, out);
}

// Round 11
// 106.827 us; speedup vs baseline: 1.1978x; 1.1978x over previous
//
#include <hip/hip_runtime.h>

#define BATCH 131072
#define NS    300
#define H     100
#define BLK   256
#define EPB   64
#define NBLK  (BATCH / EPB)        /* 2048 blocks */
#define NQ4   (EPB * NS / 4)       /* 4800 float4 outputs per block */
#define RS    140                  /* sH1 row stride in floats: 16B-aligned, 2-way banks (free) */
#define LOOFF 14336                /* lo-plane offset in ushorts = 28 frags * 64 lanes * 8 */

typedef __attribute__((ext_vector_type(8))) short bf16x8;
typedef __attribute__((ext_vector_type(4))) float f32x4;

__device__ __forceinline__ unsigned short f2bf(float f) {
    unsigned int u = __float_as_uint(f);
    unsigned int r = (u + 0x7fffu + ((u >> 16) & 1u)) >> 16;   /* RN-even */
    return (unsigned short)r;
}
__device__ __forceinline__ float bf2f(unsigned short h) {
    return __uint_as_float(((unsigned int)h) << 16);
}

/* prep: split-bf16 B-fragments of W2^T (k x n), zero-padded to 128 x 112.
   Frag (s,t): lane holds B[k = s*32 + (lane>>4)*8 + i][n = t*16 + (lane&15)].
   Same (lane-group,i)->k bijection is used for A, so any HW k-permutation cancels. */
__global__ void prep_w2(const float* __restrict__ W2, unsigned short* __restrict__ wsb) {
    const int fi   = blockIdx.x * 4 + (threadIdx.x >> 6);   /* 0..27 */
    const int lane = threadIdx.x & 63;
    const int s = fi / 7, t = fi % 7;
    const int n  = t * 16 + (lane & 15);
    const int k0 = s * 32 + ((lane >> 4) << 3);
    unsigned short* hi = wsb + ((size_t)fi * 64 + lane) * 8;
#pragma unroll
    for (int i = 0; i < 8; ++i) {
        const int k = k0 + i;
        const float v = (k < H && n < H) ? W2[n * H + k] : 0.f;
        const unsigned short h = f2bf(v);
        hi[i]         = h;
        hi[LOOFF + i] = f2bf(v - bf2f(h));
    }
}

__global__ __launch_bounds__(BLK)
void lorentz_fused(const float* __restrict__ G,   const float* __restrict__ W1,
                   const float* __restrict__ b1,  const unsigned short* __restrict__ wsb,
                   const float* __restrict__ b2,  const float* __restrict__ Ww0,
                   const float* __restrict__ Wwp, const float* __restrict__ Wg,
                   float* __restrict__ out)
{
    __shared__ __align__(16) float sH1[EPB * RS];   /* 35840 B: h1 (fp32), later h2 */
    __shared__ __align__(16) float sHead[3 * 4 * 112]; /* 5376 B, zero-padded heads */
    __shared__ __align__(16) float sP[3 * EPB * 4];    /* 3072 B params */

    const int tid = threadIdx.x;

    /* ---- stage padded head tables (consumed after the first __syncthreads) ---- */
    for (int i = tid; i < 1344; i += BLK) {
        const int type = i / 448, rem = i % 448, m = rem / 112, k = rem % 112;
        const float* src = (type == 0) ? Ww0 : (type == 1) ? Wwp : Wg;
        sHead[i] = (k < H) ? src[m * H + k] : 0.f;
    }

    /* ---- L1: thread (el=tid>>2, p=tid&3) computes h1[el][p*32 .. p*32+31]
       (k<100 real, else 0) -> fp32 LDS rows of stride RS. Same wave consumes. ---- */
    {
        const int el = tid >> 2, p = tid & 3;
        const float4* gp = (const float4*)(G + (size_t)(blockIdx.x * EPB + el) * 8);
        const float4 gA = gp[0], gB = gp[1];
        float* dst = sH1 + el * RS + p * 32;
#pragma unroll
        for (int q4 = 0; q4 < 8; ++q4) {
            float v[4];
#pragma unroll
            for (int c = 0; c < 4; ++c) {
                const int k = p * 32 + q4 * 4 + c;
                float r = 0.f;
                if (k < H) {
                    const float4 ra = ((const float4*)(W1 + k * 8))[0];
                    const float4 rb = ((const float4*)(W1 + k * 8))[1];
                    float s0 = fmaf(gA.x, ra.x, b1[k]);
                    float s1 = gA.y * ra.y;
                    s0 = fmaf(gA.z, ra.z, s0);  s1 = fmaf(gA.w, ra.w, s1);
                    s0 = fmaf(gB.x, rb.x, s0);  s1 = fmaf(gB.y, rb.y, s1);
                    s0 = fmaf(gB.z, rb.z, s0);  s1 = fmaf(gB.w, rb.w, s1);
                    r = fmaxf(s0 + s1, 0.f);
                }
                v[c] = r;
            }
            *(float4*)(dst + q4 * 4) = make_float4(v[0], v[1], v[2], v[3]);
        }
    }

    /* ---- layer 2 via MFMA, split-bf16 (hi*Hi + hi*Lo + lo*Hi).
       Wave w owns el-tile [w*16, w*16+16). No barrier needed: same-wave RAW. ---- */
    const int w = tid >> 6, lane = tid & 63, ln = lane & 15, gr = lane >> 4;
    {
        const float* arow = sH1 + (size_t)(w * 16 + ln) * RS + gr * 8;
        f32x4 acc[7];
#pragma unroll
        for (int t = 0; t < 7; ++t) acc[t] = (f32x4){0.f, 0.f, 0.f, 0.f};

        const bf16x8* Bf = (const bf16x8*)wsb;
#pragma unroll
        for (int s = 0; s < 4; ++s) {
            const float4 av0 = *(const float4*)(arow + s * 32);
            const float4 av1 = *(const float4*)(arow + s * 32 + 4);
            bf16x8 ahi, alo;
            {
                const float af0 = av0.x, af1 = av0.y, af2 = av0.z, af3 = av0.w;
                const float af4 = av1.x, af5 = av1.y, af6 = av1.z, af7 = av1.w;
#define CV(i, x) { const unsigned short h = f2bf(x); ahi[i] = (short)h; \
                   alo[i] = (short)f2bf((x) - bf2f(h)); }
                CV(0, af0) CV(1, af1) CV(2, af2) CV(3, af3)
                CV(4, af4) CV(5, af5) CV(6, af6) CV(7, af7)
#undef CV
            }
#pragma unroll
            for (int t = 0; t < 7; ++t) {
                const bf16x8 bh = Bf[(s * 7 + t) * 64 + lane];
                const bf16x8 bl = Bf[1792 + (s * 7 + t) * 64 + lane];
                acc[t] = __builtin_amdgcn_mfma_f32_16x16x32_bf16(ahi, bh, acc[t], 0, 0, 0);
                acc[t] = __builtin_amdgcn_mfma_f32_16x16x32_bf16(ahi, bl, acc[t], 0, 0, 0);
                acc[t] = __builtin_amdgcn_mfma_f32_16x16x32_bf16(alo, bh, acc[t], 0, 0, 0);
            }
        }

        /* epilogue: + b2, ReLU, write h2 back over sH1 (own tile rows only).
           C/D layout (HW-verified m89): el = w*16 + gr*4 + r, j = t*16 + ln. */
#pragma unroll
        for (int t = 0; t < 7; ++t) {
            const int n = t * 16 + ln;
            const float b2v = (n < H) ? b2[n] : 0.f;
#pragma unroll
            for (int r = 0; r < 4; ++r) {
                const int elr = w * 16 + gr * 4 + r;
                sH1[elr * RS + n] = fmaxf(acc[t][r] + b2v, 0.f);
            }
        }
    }
    __syncthreads();

    /* ---- heads (quad-split VALU): thread (el=tid>>2, m=tid&3) does 3 dots of 112 ---- */
    {
        const int el = tid >> 2, m = tid & 3;
        const float4* h2r = (const float4*)(sH1 + el * RS);
        const float4* x0 = (const float4*)(sHead + 0 * 448 + m * 112);
        const float4* x1 = (const float4*)(sHead + 1 * 448 + m * 112);
        const float4* x2 = (const float4*)(sHead + 2 * 448 + m * 112);
        float a0 = 0.f, a1 = 0.f, a2 = 0.f;
#pragma unroll
        for (int k4 = 0; k4 < 28; ++k4) {
            const float4 hq = h2r[k4];
            const float4 p = x0[k4], q = x1[k4], r = x2[k4];
            a0 = fmaf(hq.x, p.x, a0); a1 = fmaf(hq.x, q.x, a1); a2 = fmaf(hq.x, r.x, a2);
            a0 = fmaf(hq.y, p.y, a0); a1 = fmaf(hq.y, q.y, a1); a2 = fmaf(hq.y, r.y, a2);
            a0 = fmaf(hq.z, p.z, a0); a1 = fmaf(hq.z, q.z, a1); a2 = fmaf(hq.z, r.z, a2);
            a0 = fmaf(hq.w, p.w, a0); a1 = fmaf(hq.w, q.w, a1); a2 = fmaf(hq.w, r.w, a2);
        }
        const float w0 = fmaxf(a0, 0.f), wp = fmaxf(a1, 0.f), gg = fmaxf(a2, 0.f);
        sP[el * 4 + m]            = w0 * w0;
        sP[256 + el * 4 + m]      = gg * gg;
        sP[512 + el * 4 + m]      = wp * wp * gg;
    }
    __syncthreads();

    /* ---- spectrum: block's contiguous 64*300-float region (R10-proven code) ---- */
    const float4* sP0 = (const float4*)sP;
    const float4* sP1 = (const float4*)(sP + 256);
    const float4* sP2 = (const float4*)(sP + 512);
    float4* out4 = (float4*)out;
    const size_t base4 = (size_t)blockIdx.x * NQ4;

#define SPEC(idx4)                                                              \
    {   const int e  = (idx4) / 75;                                             \
        const int k4 = (idx4) - e * 75;                                         \
        const float4 P0 = sP0[e], P1 = sP1[e], P2 = sP2[e];                     \
        const float kb = (float)(k4 << 2);                                      \
        float4 r; float* rp = (float*)&r;                                       \
        _Pragma("unroll")                                                       \
        for (int i = 0; i < 4; ++i) {                                           \
            const float w_   = 0.5f + (kb + (float)i) * 0.015f;                 \
            const float wsq = w_ * w_;                                          \
            const float t0 = P0.x - wsq, t1 = P0.y - wsq,                       \
                        t2 = P0.z - wsq, t3 = P0.w - wsq;                       \
            const float d0 = fmaf(t0, t0, wsq * P1.x);                          \
            const float d1 = fmaf(t1, t1, wsq * P1.y);                          \
            const float d2 = fmaf(t2, t2, wsq * P1.z);                          \
            const float d3 = fmaf(t3, t3, wsq * P1.w);                          \
            const float d01 = d0 * d1, d23 = d2 * d3;                           \
            const float D   = d01 * d23;                                        \
            const float n01 = fmaf(P2.y, d0, P2.x * d1);                        \
            const float n23 = fmaf(P2.w, d2, P2.z * d3);                        \
            const float N   = fmaf(n01, d23, n23 * d01);                        \
            rp[i] = w_ * (N * __builtin_amdgcn_rcpf(D));                        \
        }                                                                       \
        out4[base4 + (idx4)] = r; }

    for (int it = 0; it < NQ4 / BLK; ++it) {        /* 18 iterations */
        const int idx4 = it * BLK + tid;
        SPEC(idx4)
    }
    if (tid < NQ4 - (NQ4 / BLK) * BLK) {            /* tail: 192 quads */
        const int idx4 = (NQ4 / BLK) * BLK + tid;
        SPEC(idx4)
    }
#undef SPEC
}

extern "C" void kernel_launch(void* const* d_in, const int* in_sizes, int n_in,
                              void* d_out, int out_size, void* d_ws, size_t ws_size,
                              hipStream_t stream) {
    const float* G   = (const float*)d_in[0];
    const float* W1  = (const float*)d_in[1];
    const float* b1  = (const float*)d_in[2];
    const float* W2  = (const float*)d_in[3];
    const float* b2  = (const float*)d_in[4];
    const float* Ww0 = (const float*)d_in[5];
    const float* Wwp = (const float*)d_in[6];
    const float* Wg  = (const float*)d_in[7];
    float* out = (float*)d_out;
    unsigned short* wsb = (unsigned short*)d_ws;   /* 57344 B scratch */

    prep_w2<<<7, 256, 0, stream>>>(W2, wsb);
    lorentz_fused<<<NBLK, BLK, 0, stream>>>(G, W1, b1, wsb, b2, Ww0, Wwp, Wg, out);
}